// Round 2
// baseline (219.380 us; speedup 1.0000x reference)
//
#include <hip/hip_runtime.h>
#include <stdint.h>

#define TT 12
#define NN 325
#define HH 64
#define EE 32
#define LHH 128
#define OO 12
#define CIN 97
#define MOFF 65
#define BB 64

typedef __attribute__((ext_vector_type(8))) short bf8;
typedef __attribute__((ext_vector_type(4))) float f4;

__device__ __forceinline__ float sigf(float x) {
  return __builtin_amdgcn_rcpf(1.f + __builtin_amdgcn_exp2f(-1.4426950408889634f * x));
}
__device__ __forceinline__ float tanhfast(float x) {
  // tanh(x) = 1 - 2/(1+e^{2x});  e^{2x} = 2^{2x*log2e}
  return 1.f - 2.f * __builtin_amdgcn_rcpf(1.f + __builtin_amdgcn_exp2f(2.8853900817779268f * x));
}
__device__ __forceinline__ unsigned short f2bf(float f) {  // RNE float->bf16
  unsigned int u = __float_as_uint(f);
  u += 0x7fffu + ((u >> 16) & 1u);
  return (unsigned short)(u >> 16);
}
__device__ __forceinline__ float bf2f(unsigned short s) {
  return __uint_as_float(((unsigned int)s) << 16);
}

// ---------------------------------------------------------------------------
// Kernel 1 (fused k_meta + k_wh): grid 1024 = (4 g x 64 col-slices x 4
// batch-quarters). Every block recomputes the 16-batch meta mean (~24 KB of
// L2-hit reads) and its gate's lwh hidden locally (~100 K FMA) -- cheaper
// than a device-wide kernel boundary. Main duty: hid(16b x 128) @ W2-slice
// (128 x 64) -> bf16 Wh in MFMA B-frag order (byte-identical formula).
// Extra duty: blocks i==0 -> wx_ws, i==1 -> bg_ws for their (g, 16 batches).
// ---------------------------------------------------------------------------
__global__ __launch_bounds__(256) void k_prep(
    const float* __restrict__ x,
    const float* __restrict__ xw1, const float* __restrict__ xb1,
    const float* __restrict__ xw2, const float* __restrict__ xb2,
    const float* __restrict__ hw1, const float* __restrict__ hb1,
    const float* __restrict__ hw2, const float* __restrict__ hb2,
    const float* __restrict__ bw1, const float* __restrict__ bb1,
    const float* __restrict__ bw2, const float* __restrict__ bb2,
    unsigned short* __restrict__ whb,
    float* __restrict__ wx_ws, float* __restrict__ bg_ws)
{
  const int g = blockIdx.x >> 8, i = (blockIdx.x >> 2) & 63, bq = blockIdx.x & 3;
  const int tid = threadIdx.x;
  __shared__ float meta_s[16][EE];
  __shared__ float hs[16][132];    // hidden [b16][l], padded (rows 528B)
  __shared__ float w2s[LHH][HH];   // W2 slice [l][j]

  // meta mean for batches bq*16 .. bq*16+15 (512 (b,e) pairs, 2 per thread;
  // lanes sweep e -> 128B coalesced rows, L2-resident after first touch)
  #pragma unroll
  for (int k = 0; k < 2; ++k) {
    const int idx = tid + 256 * k;
    const int b16 = idx >> 5, e = idx & 31;
    const int b = bq * 16 + b16;
    float s = 0.f;
    #pragma unroll
    for (int t = 0; t < TT; ++t)
      s += x[(size_t)((b * TT + t) * NN) * CIN + MOFF + e];
    meta_s[b16][e] = s * (1.f / 12.f);
  }
  __syncthreads();

  // lwh hidden for gate g, 16 batches (same fmaf order as before -> whb
  // bit-identical to the 3-kernel version)
  for (int idx = tid; idx < 16 * LHH; idx += 256) {
    const int b16 = idx >> 7, l = idx & 127;
    float a = hb1[g * LHH + l];
    const float* w = hw1 + (size_t)g * (EE * LHH) + l;
    #pragma unroll
    for (int e = 0; e < EE; ++e) a = fmaf(meta_s[b16][e], w[e * LHH], a);
    hs[b16][l] = fmaxf(a, 0.f);
  }
  for (int idx = tid; idx < LHH * HH; idx += 256)
    w2s[idx >> 6][idx & 63] =
        hw2[(size_t)(g * LHH + (idx >> 6)) * 4096 + i * 64 + (idx & 63)];
  __syncthreads();

  // 2 rows x 2 cols per thread over K=128
  {
    const int r0 = (tid >> 5) * 2, j0 = (tid & 31) * 2;
    float acc[2][2] = {};
    for (int l = 0; l < LHH; l += 4) {
      const f4 h0 = *(const f4*)&hs[r0][l];
      const f4 h1 = *(const f4*)&hs[r0 + 1][l];
      #pragma unroll
      for (int ll = 0; ll < 4; ++ll) {
        const float w0 = w2s[l + ll][j0];
        const float w1 = w2s[l + ll][j0 + 1];
        acc[0][0] = fmaf(h0[ll], w0, acc[0][0]);
        acc[0][1] = fmaf(h0[ll], w1, acc[0][1]);
        acc[1][0] = fmaf(h1[ll], w0, acc[1][0]);
        acc[1][1] = fmaf(h1[ll], w1, acc[1][1]);
      }
    }

    // store bf16 in MFMA B-frag order (same formula as before)
    const int kh = i >> 5, quad = (i >> 3) & 3, j8 = i & 7;
    #pragma unroll
    for (int rr = 0; rr < 2; ++rr) {
      const int b = bq * 16 + r0 + rr;
      #pragma unroll
      for (int jj = 0; jj < 2; ++jj) {
        const int j = j0 + jj;
        const float v = acc[rr][jj] + hb2[g * 4096 + i * 64 + j];
        const int col = g * 64 + j;
        const int nt = col >> 4, c16 = col & 15;
        const int lane = quad * 16 + c16;
        whb[(size_t)((b * 32 + kh * 16 + nt) * 64 + lane) * 8 + j8] = f2bf(v);
      }
    }
  }

  // extra duty: i==0 -> wx_ws (lwx MLP), i==1 -> bg_ws (lb MLP).
  // block-uniform branch; reuses hs/w2s after a barrier.
  if (i < 2) {
    const float* W1 = i ? bw1 : xw1;
    const float* B1 = i ? bb1 : xb1;
    const float* W2 = i ? bw2 : xw2;
    const float* B2 = i ? bb2 : xb2;
    float* dst = i ? bg_ws : wx_ws;
    __syncthreads();  // main-duty reads of hs/w2s done before overwrite
    for (int idx = tid; idx < 16 * LHH; idx += 256) {
      const int b16 = idx >> 7, l = idx & 127;
      float a = B1[g * LHH + l];
      const float* w = W1 + (size_t)g * (EE * LHH) + l;
      #pragma unroll
      for (int e = 0; e < EE; ++e) a = fmaf(meta_s[b16][e], w[e * LHH], a);
      hs[b16][l] = fmaxf(a, 0.f);
    }
    for (int idx = tid; idx < LHH * HH; idx += 256)
      w2s[idx >> 6][idx & 63] =
          W2[(size_t)(g * LHH + (idx >> 6)) * HH + (idx & 63)];
    __syncthreads();
    for (int idx = tid; idx < 16 * HH; idx += 256) {
      const int b16 = idx >> 6, h = idx & 63;
      float a = B2[g * HH + h];
      #pragma unroll 4
      for (int l = 0; l < LHH; ++l)
        a = fmaf(hs[b16][l], w2s[l][h], a);
      dst[(bq * 16 + b16) * 256 + g * 64 + h] = a;
    }
  }
}

// ---------------------------------------------------------------------------
// Kernel 2 (k_lstm): grid (11 x-tiles of 32 rows, 64 batches). Identical to
// previous version except it gathers its own x-signal tile directly from x
// (stride-97 reads, 384 lines/block) instead of the xg workspace round-trip.
// ---------------------------------------------------------------------------
__global__ __launch_bounds__(256, 3) void k_lstm(
    const float* __restrict__ x, const float* __restrict__ wx_ws,
    const float* __restrict__ bg_ws, const unsigned short* __restrict__ whb,
    const float* __restrict__ fc1W, const float* __restrict__ fc1b,
    const float* __restrict__ fc2W, const float* __restrict__ fc2b,
    float* __restrict__ out)
{
  const int rb = blockIdx.x, b = blockIdx.y, tid = threadIdx.x;
  const int wave = tid >> 6, lane = tid & 63, quad = lane >> 4, c16 = lane & 15;
  const int n0 = rb * 32;

  __shared__ __align__(16) unsigned short Hs[2][2][16][72];  // [buf][tile][row][col]
  __shared__ float Xs[TT][32];
  __shared__ float fc1s[HH * 32];
  __shared__ float fc2s[32 * OO];
  __shared__ float HIDs[32][36];
  __shared__ float fc1bs[32];
  __shared__ float fc2bs[OO];

  for (int idx = tid; idx < TT * 32; idx += 256) {
    const int t = idx >> 5, r = idx & 31, n = n0 + r;
    Xs[t][r] = (n < NN) ? x[(size_t)((b * TT + t) * NN + n) * CIN] : 0.f;
  }
  for (int idx = tid; idx < HH * 32; idx += 256) fc1s[idx] = fc1W[idx];
  for (int idx = tid; idx < 32 * OO; idx += 256) fc2s[idx] = fc2W[idx];
  if (tid < 32) fc1bs[tid] = fc1b[tid];
  if (tid < OO) fc2bs[tid] = fc2b[tid];

  float wxv[4], bgv[4];
  #pragma unroll
  for (int g = 0; g < 4; ++g) {
    wxv[g] = wx_ws[b * 256 + g * 64 + wave * 16 + c16];
    bgv[g] = bg_ws[b * 256 + g * 64 + wave * 16 + c16];
  }
  bf8 wf[2][4];
  #pragma unroll
  for (int kh = 0; kh < 2; ++kh)
    #pragma unroll
    for (int g = 0; g < 4; ++g)
      wf[kh][g] = *(const bf8*)(whb + (size_t)((b * 32 + kh * 16 + g * 4 + wave) * 64 + lane) * 8);

  float cst[2][4];
  #pragma unroll
  for (int ta = 0; ta < 2; ++ta)
    #pragma unroll
    for (int r = 0; r < 4; ++r) cst[ta][r] = 0.f;

  __syncthreads();

  #pragma unroll 1
  for (int t = 0; t < TT; ++t) {
    bf8 af[2][2];
    if (t > 0) {
      #pragma unroll
      for (int ta = 0; ta < 2; ++ta) {
        af[ta][0] = *(const bf8*)&Hs[(t - 1) & 1][ta][c16][quad * 8];
        af[ta][1] = *(const bf8*)&Hs[(t - 1) & 1][ta][c16][32 + quad * 8];
      }
    }
    f4 ac[2][4];
    #pragma unroll
    for (int ta = 0; ta < 2; ++ta) {
      float xr[4];
      #pragma unroll
      for (int r = 0; r < 4; ++r) xr[r] = Xs[t][ta * 16 + quad * 4 + r];
      #pragma unroll
      for (int g = 0; g < 4; ++g)
        #pragma unroll
        for (int r = 0; r < 4; ++r)
          ac[ta][g][r] = fmaf(xr[r], wxv[g], bgv[g]);
    }
    if (t > 0) {
      #pragma unroll
      for (int ta = 0; ta < 2; ++ta)
        #pragma unroll
        for (int g = 0; g < 4; ++g) {
          ac[ta][g] = __builtin_amdgcn_mfma_f32_16x16x32_bf16(af[ta][0], wf[0][g], ac[ta][g], 0, 0, 0);
          ac[ta][g] = __builtin_amdgcn_mfma_f32_16x16x32_bf16(af[ta][1], wf[1][g], ac[ta][g], 0, 0, 0);
        }
    }
    #pragma unroll
    for (int ta = 0; ta < 2; ++ta)
      #pragma unroll
      for (int r = 0; r < 4; ++r) {
        const float gg = tanhfast(ac[ta][0][r]);
        const float ii = sigf(ac[ta][1][r]);
        const float ff = sigf(ac[ta][2][r]);
        const float oo = sigf(ac[ta][3][r]);
        const float cc = fmaf(gg, ii, cst[ta][r] * ff);
        cst[ta][r] = cc;
        const float hh = tanhfast(cc) * oo;
        Hs[t & 1][ta][quad * 4 + r][wave * 16 + c16] = f2bf(hh);
      }
    __syncthreads();
  }

  // ---- head, fp32. final h is in Hs[1]. ----
  {
    const int row32 = tid & 31, uu = tid >> 5;
    const int ta = row32 >> 4, row = row32 & 15;
    float hacc[4];
    #pragma unroll
    for (int j = 0; j < 4; ++j) hacc[j] = fc1bs[uu * 4 + j];
    #pragma unroll
    for (int kc = 0; kc < 8; ++kc) {
      const bf8 hv = *(const bf8*)&Hs[1][ta][row][kc * 8];
      #pragma unroll
      for (int j8 = 0; j8 < 8; ++j8) {
        const float hk = fmaxf(bf2f((unsigned short)hv[j8]), 0.f);  // relu(h)
        const int k = kc * 8 + j8;
        #pragma unroll
        for (int j = 0; j < 4; ++j)
          hacc[j] = fmaf(hk, fc1s[k * 32 + uu * 4 + j], hacc[j]);
      }
    }
    #pragma unroll
    for (int j = 0; j < 4; ++j)
      HIDs[row32][uu * 4 + j] = fmaxf(hacc[j], 0.f);
  }
  __syncthreads();
  for (int idx = tid; idx < 32 * OO; idx += 256) {
    const int o = idx >> 5, row32 = idx & 31;
    float a = fc2bs[o];
    #pragma unroll
    for (int k = 0; k < 32; ++k)
      a = fmaf(HIDs[row32][k], fc2s[k * OO + o], a);
    const int n = n0 + row32;
    if (n < NN)
      out[b * (OO * NN) + o * NN + n] = a;
  }
}

// ---------------------------------------------------------------------------
extern "C" void kernel_launch(void* const* d_in, const int* in_sizes, int n_in,
                              void* d_out, int out_size, void* d_ws, size_t ws_size,
                              hipStream_t stream) {
  const float* x    = (const float*)d_in[0];
  const float* xw1  = (const float*)d_in[1];
  const float* xb1  = (const float*)d_in[2];
  const float* xw2  = (const float*)d_in[3];
  const float* xb2  = (const float*)d_in[4];
  const float* hw1  = (const float*)d_in[5];
  const float* hb1  = (const float*)d_in[6];
  const float* hw2  = (const float*)d_in[7];
  const float* hb2  = (const float*)d_in[8];
  const float* bw1  = (const float*)d_in[9];
  const float* bb1  = (const float*)d_in[10];
  const float* bw2  = (const float*)d_in[11];
  const float* bb2  = (const float*)d_in[12];
  const float* fc1W = (const float*)d_in[13];
  const float* fc1b = (const float*)d_in[14];
  const float* fc2W = (const float*)d_in[15];
  const float* fc2b = (const float*)d_in[16];
  float* out = (float*)d_out;

  float* ws = (float*)d_ws;
  float* wx_ws = ws;                         // [64][256] = 16384 floats
  float* bg_ws = ws + 16384;                 // [64][256] = 16384 floats
  unsigned short* whb = (unsigned short*)(ws + 32768);  // 1048576 u16

  k_prep<<<1024, 256, 0, stream>>>(x, xw1, xb1, xw2, xb2, hw1, hb1, hw2, hb2,
                                   bw1, bb1, bw2, bb2, whb, wx_ws, bg_ws);
  k_lstm<<<dim3(11, 64), 256, 0, stream>>>(x, wx_ws, bg_ws, whb,
                                           fc1W, fc1b, fc2W, fc2b, out);
}